// Round 1
// baseline (324.257 us; speedup 1.0000x reference)
//
#include <hip/hip_runtime.h>
#include <hip/hip_bf16.h>
#include <cstdint>
#include <cstddef>

#define B 64
#define T 1024
#define DQ 1024
#define DV 512
#define A_DIM 512
#define F_DIM 32
#define KW 31
#define M_TOT (B*T)
#define KEXT2 576     // DV + 64 (conv 32 + zero-pad 32)
#define NCH 9         // 9 chunks of K=64 (last = conv+pad)

typedef __attribute__((ext_vector_type(8))) short short8;
typedef __attribute__((ext_vector_type(4))) float f32x4;

static __device__ __forceinline__ unsigned short f2bf(float f) {
    unsigned int u = __builtin_bit_cast(unsigned int, f);
    u += 0x7fffu + ((u >> 16) & 1u);   // RNE
    return (unsigned short)(u >> 16);
}
static __device__ __forceinline__ short8 pack8(float4 x0, float4 x1) {
    short8 pk;
    pk[0] = (short)f2bf(x0.x); pk[1] = (short)f2bf(x0.y);
    pk[2] = (short)f2bf(x0.z); pk[3] = (short)f2bf(x0.w);
    pk[4] = (short)f2bf(x1.x); pk[5] = (short)f2bf(x1.y);
    pk[6] = (short)f2bf(x1.z); pk[7] = (short)f2bf(x1.w);
    return pk;
}
static __device__ __forceinline__ float tanh_fast(float x) {
    float e = __expf(2.0f * x);
    return 1.0f - 2.0f * __builtin_amdgcn_rcpf(e + 1.0f);
}

// async global -> LDS, 16 B per lane; lptr wave-uniform base, lane i -> +i*16
#define LDSDMA16(gptr, lptr)                                                        \
    __builtin_amdgcn_global_load_lds(                                               \
        (const __attribute__((address_space(1))) void*)(const void*)(gptr),         \
        (__attribute__((address_space(3))) void*)(void*)(lptr), 16, 0, 0)

// ================= prep (no values pass) =================
// blocks [0,512): pq + score zero   [512,584): B_ext^T transpose
// [584,1608): location conv
__global__ void prep_kernel(const float* __restrict__ query, const float* __restrict__ Wq,
                            const float* __restrict__ Wi, const float* __restrict__ Wl,
                            const float* __restrict__ old_, const float* __restrict__ cum_,
                            const float* __restrict__ lk,
                            float* __restrict__ pq,
                            float* __restrict__ score, unsigned short* __restrict__ Bt,
                            unsigned short* __restrict__ convb) {
    __shared__ __align__(16) char smem[16640];
    int bid = blockIdx.x, tid = threadIdx.x;
    if (bid < 512) {
        // ---- pq + zero score ----
        float (*red)[64] = (float(*)[64])smem;
        int pid = bid;
        int gid = pid * 256 + tid;
        if (gid < M_TOT) score[gid] = 0.f;
        int b = pid >> 3, a0 = (pid & 7) * 64;
        int al = tid & 63, ks = tid >> 6;
        const float* qr = query + (size_t)b * DQ + ks * 256;
        const float* wc = Wq + (size_t)(ks * 256) * A_DIM + a0 + al;
        float acc = 0.f;
        #pragma unroll 8
        for (int k = 0; k < 256; ++k) acc += qr[k] * wc[(size_t)k * A_DIM];
        red[ks][al] = acc;
        __syncthreads();
        if (ks == 0)
            pq[b * A_DIM + a0 + al] = red[0][al] + red[1][al] + red[2][al] + red[3][al];
    } else if (bid < 584) {
        // ---- Bt transpose (stride KEXT2=576) ----
        float (*tile)[65] = (float(*)[65])smem;
        int tb = bid - 512;
        if (tb < 64) {
            int k0 = (tb >> 3) * 64, a0 = (tb & 7) * 64;
            int al = tid & 63, ko = tid >> 6;
            #pragma unroll
            for (int j = 0; j < 16; ++j) {
                int kl = j * 4 + ko;
                tile[kl][al] = Wi[(size_t)(k0 + kl) * A_DIM + a0 + al];
            }
            __syncthreads();
            int kl2 = tid & 63, ao = tid >> 6;
            #pragma unroll
            for (int j = 0; j < 16; ++j) {
                int al2 = j * 4 + ao;
                Bt[(size_t)(a0 + al2) * KEXT2 + k0 + kl2] = f2bf(tile[kl2][al2]);
            }
        } else {
            int a0 = (tb - 64) * 64;
            int al = tid & 63, ko = tid >> 6;
            #pragma unroll
            for (int j = 0; j < 8; ++j) {
                int kl = j * 4 + ko;
                tile[kl][al] = Wl[(size_t)kl * A_DIM + a0 + al];
            }
            __syncthreads();
            int kl2 = tid & 31, ao = tid >> 5;
            #pragma unroll
            for (int j = 0; j < 8; ++j) {
                int al2 = j * 8 + ao;
                Bt[(size_t)(a0 + al2) * KEXT2 + DV + kl2] = f2bf(tile[kl2][al2]);
            }
            // zero-pad k in [544,576)
            #pragma unroll
            for (int j = 0; j < 8; ++j) {
                int idx = j * 256 + tid;
                int a_l = idx >> 5, kp = idx & 31;
                Bt[(size_t)(a0 + a_l) * KEXT2 + 544 + kp] = 0;
            }
        }
    } else {
        // ---- conv (rows widened to 64: [32 conv | 32 zeros]) ----
        float* sOld = (float*)smem;            // 94
        float* sCum = sOld + 94;               // 94
        float* sLK  = sCum + 94;               // 1984
        int cid = bid - 584;
        int b = cid >> 4, t0 = (cid & 15) * 64;
        int tl = tid & 63, fg = tid >> 6;
        for (int j = tid; j < 94; j += 256) {
            int tt = t0 - 15 + j;
            bool ok = (tt >= 0 && tt < T);
            sOld[j] = ok ? old_[b * T + tt] : 0.f;
            sCum[j] = ok ? cum_[b * T + tt] : 0.f;
        }
        for (int j = tid; j < KW * 2 * F_DIM; j += 256) sLK[j] = lk[j];
        __syncthreads();
        float acc[8];
        #pragma unroll
        for (int f = 0; f < 8; ++f) acc[f] = 0.f;
        for (int k = 0; k < KW; ++k) {
            float o = sOld[tl + k], c = sCum[tl + k];
            const float* lo = &sLK[(k * 2 + 0) * F_DIM + fg * 8];
            const float* lc = &sLK[(k * 2 + 1) * F_DIM + fg * 8];
            #pragma unroll
            for (int f = 0; f < 8; ++f) acc[f] += o * lo[f] + c * lc[f];
        }
        short8 pk;
        #pragma unroll
        for (int f = 0; f < 8; ++f) pk[f] = (short)f2bf(acc[f]);
        unsigned short* dst = convb + (size_t)(b * T + t0 + tl) * 64 + fg * 8;
        *(short8*)dst = pk;
        *(short8*)(dst + 32) = (short8)0;      // zero-pad
    }
}

// ================= fused GEMM + tanh + dot(v_w) -> score =================
// grid 2048 XCD-swizzled; block 128x128, BK=64, 9 chunks; 4 waves, wave 64x64
// LDS 8-slot XOR swizzle: 16B-slot' = (seg + row) & 7
// A (values) staged fp32->bf16 in-register (no separate conversion pass);
// conv chunk (c==8) staged via global_load_lds from bf16 convb.
__launch_bounds__(256, 3)
__global__ void gemm_score(const float* __restrict__ values,
                           const unsigned short* __restrict__ Bt,
                           const unsigned short* __restrict__ convb,
                           const float* __restrict__ pq,
                           const float* __restrict__ vw,
                           float* __restrict__ score) {
    __shared__ __align__(16) short sA[128 * 64];
    __shared__ __align__(16) short sB[128 * 64];
    __shared__ float sPQ[128];
    __shared__ float sVW[128];
    int tid = threadIdx.x;
    // XCD swizzle: 4 nq-siblings (same mt) land on one XCD, adjacent in time
    int x = blockIdx.x & 7, l = blockIdx.x >> 3;
    int mt = x * 64 + (l >> 2), nq = l & 3;
    int m0 = mt * 128, n0 = nq * 128;
    int b = m0 >> 10;
    if (tid < 128) { sPQ[tid] = pq[b * A_DIM + n0 + tid]; sVW[tid] = vw[n0 + tid]; }
    int w = tid >> 6, lane = tid & 63, q = lane >> 4, l15 = lane & 15;
    int wm = w & 1, wn = w >> 1;
    // per-thread A staging geometry hoisted out of the chunk loop
    const float* aSrc[4];
    int aSlot[4];
    #pragma unroll
    for (int jj = 0; jj < 4; ++jj) {
        int slot = tid * 4 + jj;
        int row = slot >> 3, sl = slot & 7, seg = (sl - row) & 7;
        aSrc[jj] = values + (size_t)(m0 + row) * DV + seg * 8;
        aSlot[jj] = slot;
    }
    f32x4 acc[4][4];
    #pragma unroll
    for (int mi = 0; mi < 4; ++mi)
        #pragma unroll
        for (int ni = 0; ni < 4; ++ni) acc[mi][ni] = (f32x4)0.f;

    for (int c = 0; c < NCH; ++c) {
        __syncthreads();
        // ---- B stage: async DMA, 1024 slots of 16B per tile
        #pragma unroll
        for (int j = 0; j < 4; ++j) {
            int slot = j * 256 + tid;
            int row = slot >> 3, seg = ((slot & 7) - row) & 7;
            const unsigned short* gB = Bt + (size_t)(n0 + row) * KEXT2 + c * 64 + seg * 8;
            LDSDMA16(gB, &sB[(j * 256 + w * 64) * 8]);
        }
        // ---- A stage: fp32 load + in-register bf16 pack (c<8), DMA for conv chunk
        if (c < 8) {
            float4 x0[4], x1[4];
            #pragma unroll
            for (int jj = 0; jj < 4; ++jj) {
                const float* s0 = aSrc[jj] + c * 64;
                x0[jj] = *(const float4*)s0;
                x1[jj] = *(const float4*)(s0 + 4);
            }
            #pragma unroll
            for (int jj = 0; jj < 4; ++jj)
                *(short8*)&sA[aSlot[jj] * 8] = pack8(x0[jj], x1[jj]);
        } else {
            #pragma unroll
            for (int j = 0; j < 4; ++j) {
                int slot = j * 256 + tid;
                int row = slot >> 3, seg = ((slot & 7) - row) & 7;
                LDSDMA16(convb + (size_t)(m0 + row) * 64 + seg * 8,
                         &sA[(j * 256 + w * 64) * 8]);
            }
        }
        __syncthreads();
        // ---- 2 k-halves x 16 MFMAs
        #pragma unroll
        for (int h = 0; h < 2; ++h) {
            short8 af[4], bfr[4];
            int sgl = h * 4 + q;
            #pragma unroll
            for (int mi = 0; mi < 4; ++mi) {
                int r = wm * 64 + mi * 16 + l15;
                af[mi] = *(const short8*)&sA[r * 64 + (((sgl + r) & 7) << 3)];
            }
            #pragma unroll
            for (int ni = 0; ni < 4; ++ni) {
                int r = wn * 64 + ni * 16 + l15;
                bfr[ni] = *(const short8*)&sB[r * 64 + (((sgl + r) & 7) << 3)];
            }
            #pragma unroll
            for (int mi = 0; mi < 4; ++mi)
                #pragma unroll
                for (int ni = 0; ni < 4; ++ni)
                    acc[mi][ni] = __builtin_amdgcn_mfma_f32_16x16x32_bf16(af[mi], bfr[ni], acc[mi][ni], 0, 0, 0);
        }
    }
    // ---- epilogue: partial score over 128 cols -> atomicAdd
    #pragma unroll
    for (int mi = 0; mi < 4; ++mi) {
        #pragma unroll
        for (int r = 0; r < 4; ++r) {
            float s = 0.f;
            #pragma unroll
            for (int ni = 0; ni < 4; ++ni) {
                int col = wn * 64 + ni * 16 + l15;
                float xv = acc[mi][ni][r] + sPQ[col];
                s += tanh_fast(xv) * sVW[col];
            }
            #pragma unroll
            for (int off = 1; off < 16; off <<= 1) s += __shfl_xor(s, off, 64);
            if (l15 == 0)
                atomicAdd(&score[m0 + wm * 64 + mi * 16 + q * 4 + r], s);
        }
    }
}

// ================= softmax + forward-attention recursion =================
__global__ void softmax_fwd(const float* __restrict__ score,
                            const float* __restrict__ alpha,
                            const float* __restrict__ cum,
                            float* __restrict__ out) {
    int b = blockIdx.x, t = threadIdx.x;   // 1024 threads
    __shared__ float sred[16];
    __shared__ float sbc;
    float sc = score[b * T + t];
    int wid = t >> 6, lane = t & 63;
    float m = sc;
    #pragma unroll
    for (int off = 32; off; off >>= 1) m = fmaxf(m, __shfl_xor(m, off, 64));
    if (lane == 0) sred[wid] = m;
    __syncthreads();
    if (t == 0) { float mm = sred[0]; for (int i = 1; i < 16; ++i) mm = fmaxf(mm, sred[i]); sbc = mm; }
    __syncthreads();
    float M = sbc;
    float e = __expf(sc - M);
    float s = e;
    #pragma unroll
    for (int off = 32; off; off >>= 1) s += __shfl_xor(s, off, 64);
    __syncthreads();
    if (lane == 0) sred[wid] = s;
    __syncthreads();
    if (t == 0) { float ss = 0.f; for (int i = 0; i < 16; ++i) ss += sred[i]; sbc = ss; }
    __syncthreads();
    float sn = e / sbc;
    float a_t = alpha[b * T + t];
    float a_p = (t > 0) ? alpha[b * T + t - 1] : 0.f;
    float ua = (0.5f * (a_t + a_p) + 1e-8f) * sn;
    float u = ua;
    #pragma unroll
    for (int off = 32; off; off >>= 1) u += __shfl_xor(u, off, 64);
    __syncthreads();
    if (lane == 0) sred[wid] = u;
    __syncthreads();
    if (t == 0) { float ss = 0.f; for (int i = 0; i < 16; ++i) ss += sred[i]; sbc = ss; }
    __syncthreads();
    float wgt = ua / sbc;
    float* attnw  = out + B * DV;
    float* ncum   = attnw + B * T;
    float* nold   = ncum + B * T;
    float* nalpha = nold + B * T;
    attnw[b * T + t]  = wgt;
    ncum[b * T + t]   = cum[b * T + t] + sn;
    nold[b * T + t]   = wgt;
    nalpha[b * T + t] = wgt;
    if (t < DV) out[b * DV + t] = 0.f;   // zero context region for accumulation
}

// ================= context = attn_weights @ values (fp32) =================
// grid 512 = 64 b x 4 tq(256 t) x 2 dh(256 d); thr: sub=tid>>6 (t-slice), dg=tid&63 (4 d)
__global__ void context_kernel(const float* __restrict__ values,
                               float* __restrict__ out) {
    __shared__ float red[4][256];
    const float* attnw = out + B * DV;
    int b = blockIdx.x >> 3, tq = (blockIdx.x >> 1) & 3, dh = blockIdx.x & 1;
    int sub = threadIdx.x >> 6, dg = threadIdx.x & 63;
    int t0 = tq * 256 + sub * 64;
    int d0 = dh * 256 + dg * 4;
    float acc[4];
    #pragma unroll
    for (int f = 0; f < 4; ++f) acc[f] = 0.f;
    for (int tt = 0; tt < 64; ++tt) {
        int t = t0 + tt;
        float wgt = attnw[b * T + t];
        float4 xv = *(const float4*)(values + (size_t)(b * T + t) * DV + d0);
        acc[0] += wgt * xv.x; acc[1] += wgt * xv.y;
        acc[2] += wgt * xv.z; acc[3] += wgt * xv.w;
    }
    #pragma unroll
    for (int f = 0; f < 4; ++f) red[sub][dg * 4 + f] = acc[f];
    __syncthreads();
    if (sub == 0) {
        #pragma unroll
        for (int f = 0; f < 4; ++f) {
            int di = dg * 4 + f;
            float s = red[0][di] + red[1][di] + red[2][di] + red[3][di];
            atomicAdd(&out[b * DV + dh * 256 + di], s);
        }
    }
}

extern "C" void kernel_launch(void* const* d_in, const int* in_sizes, int n_in,
                              void* d_out, int out_size, void* d_ws, size_t ws_size,
                              hipStream_t stream) {
    const float* query  = (const float*)d_in[0];
    const float* values = (const float*)d_in[1];
    const float* cum    = (const float*)d_in[2];
    const float* old_   = (const float*)d_in[3];
    const float* alpha  = (const float*)d_in[4];
    const float* Wq     = (const float*)d_in[5];
    const float* Wi     = (const float*)d_in[6];
    const float* vw     = (const float*)d_in[7];
    // d_in[8] = v_b : dropped (softmax shift-invariant)
    const float* lk     = (const float*)d_in[9];
    const float* Wl     = (const float*)d_in[10];
    float* out = (float*)d_out;
    char* ws = (char*)d_ws;
    float* ws_pq            = (float*)(ws);                     // 128 KiB
    float* ws_score         = (float*)(ws + 131072);            // 256 KiB
    unsigned short* ws_Bt   = (unsigned short*)(ws + 393216);   // 512*576*2 = 576 KiB
    unsigned short* ws_conv = (unsigned short*)(ws + 1048576);  // 65536*64*2 = 8 MiB

    prep_kernel<<<1608, 256, 0, stream>>>(query, Wq, Wi, Wl, old_, cum, lk,
                                          ws_pq, ws_score, ws_Bt, ws_conv);
    gemm_score<<<2048, 256, 0, stream>>>(values, ws_Bt, ws_conv, ws_pq, vw, ws_score);
    softmax_fwd<<<64, 1024, 0, stream>>>(ws_score, alpha, cum, out);
    context_kernel<<<512, 256, 0, stream>>>(values, out);
}

// Round 2
// 319.061 us; speedup vs baseline: 1.0163x; 1.0163x over previous
//
#include <hip/hip_runtime.h>
#include <hip/hip_bf16.h>
#include <cstdint>
#include <cstddef>

#define B 64
#define T 1024
#define DQ 1024
#define DV 512
#define A_DIM 512
#define F_DIM 32
#define KW 31
#define M_TOT (B*T)
#define KEXT2 576     // DV + 64 (conv 32 + zero-pad 32)
#define NCH 9         // 9 chunks of K=64 (last = conv+pad)

typedef __attribute__((ext_vector_type(8))) short short8;
typedef __attribute__((ext_vector_type(4))) float f32x4;

static __device__ __forceinline__ unsigned short f2bf(float f) {
    unsigned int u = __builtin_bit_cast(unsigned int, f);
    u += 0x7fffu + ((u >> 16) & 1u);   // RNE
    return (unsigned short)(u >> 16);
}
static __device__ __forceinline__ short8 pack8(float4 x0, float4 x1) {
    short8 pk;
    pk[0] = (short)f2bf(x0.x); pk[1] = (short)f2bf(x0.y);
    pk[2] = (short)f2bf(x0.z); pk[3] = (short)f2bf(x0.w);
    pk[4] = (short)f2bf(x1.x); pk[5] = (short)f2bf(x1.y);
    pk[6] = (short)f2bf(x1.z); pk[7] = (short)f2bf(x1.w);
    return pk;
}
static __device__ __forceinline__ float tanh_fast(float x) {
    float e = __expf(2.0f * x);
    return 1.0f - 2.0f * __builtin_amdgcn_rcpf(e + 1.0f);
}

// async global -> LDS, 16 B per lane; lptr wave-uniform base, lane i -> +i*16
#define LDSDMA16(gptr, lptr)                                                        \
    __builtin_amdgcn_global_load_lds(                                               \
        (const __attribute__((address_space(1))) void*)(const void*)(gptr),         \
        (__attribute__((address_space(3))) void*)(void*)(lptr), 16, 0, 0)

// ================= prep (no values pass) =================
// blocks [0,512): pq + score zero   [512,584): B_ext^T transpose
// [584,1608): location conv
__global__ void prep_kernel(const float* __restrict__ query, const float* __restrict__ Wq,
                            const float* __restrict__ Wi, const float* __restrict__ Wl,
                            const float* __restrict__ old_, const float* __restrict__ cum_,
                            const float* __restrict__ lk,
                            float* __restrict__ pq,
                            float* __restrict__ score, unsigned short* __restrict__ Bt,
                            unsigned short* __restrict__ convb) {
    __shared__ __align__(16) char smem[16640];
    int bid = blockIdx.x, tid = threadIdx.x;
    if (bid < 512) {
        // ---- pq + zero score ----
        float (*red)[64] = (float(*)[64])smem;
        int pid = bid;
        int gid = pid * 256 + tid;
        if (gid < M_TOT) score[gid] = 0.f;
        int b = pid >> 3, a0 = (pid & 7) * 64;
        int al = tid & 63, ks = tid >> 6;
        const float* qr = query + (size_t)b * DQ + ks * 256;
        const float* wc = Wq + (size_t)(ks * 256) * A_DIM + a0 + al;
        float acc = 0.f;
        #pragma unroll 8
        for (int k = 0; k < 256; ++k) acc += qr[k] * wc[(size_t)k * A_DIM];
        red[ks][al] = acc;
        __syncthreads();
        if (ks == 0)
            pq[b * A_DIM + a0 + al] = red[0][al] + red[1][al] + red[2][al] + red[3][al];
    } else if (bid < 584) {
        // ---- Bt transpose (stride KEXT2=576) ----
        float (*tile)[65] = (float(*)[65])smem;
        int tb = bid - 512;
        if (tb < 64) {
            int k0 = (tb >> 3) * 64, a0 = (tb & 7) * 64;
            int al = tid & 63, ko = tid >> 6;
            #pragma unroll
            for (int j = 0; j < 16; ++j) {
                int kl = j * 4 + ko;
                tile[kl][al] = Wi[(size_t)(k0 + kl) * A_DIM + a0 + al];
            }
            __syncthreads();
            int kl2 = tid & 63, ao = tid >> 6;
            #pragma unroll
            for (int j = 0; j < 16; ++j) {
                int al2 = j * 4 + ao;
                Bt[(size_t)(a0 + al2) * KEXT2 + k0 + kl2] = f2bf(tile[kl2][al2]);
            }
        } else {
            int a0 = (tb - 64) * 64;
            int al = tid & 63, ko = tid >> 6;
            #pragma unroll
            for (int j = 0; j < 8; ++j) {
                int kl = j * 4 + ko;
                tile[kl][al] = Wl[(size_t)kl * A_DIM + a0 + al];
            }
            __syncthreads();
            int kl2 = tid & 31, ao = tid >> 5;
            #pragma unroll
            for (int j = 0; j < 8; ++j) {
                int al2 = j * 8 + ao;
                Bt[(size_t)(a0 + al2) * KEXT2 + DV + kl2] = f2bf(tile[kl2][al2]);
            }
            // zero-pad k in [544,576)
            #pragma unroll
            for (int j = 0; j < 8; ++j) {
                int idx = j * 256 + tid;
                int a_l = idx >> 5, kp = idx & 31;
                Bt[(size_t)(a0 + a_l) * KEXT2 + 544 + kp] = 0;
            }
        }
    } else {
        // ---- conv (rows widened to 64: [32 conv | 32 zeros]) ----
        float* sOld = (float*)smem;            // 94
        float* sCum = sOld + 94;               // 94
        float* sLK  = sCum + 94;               // 1984
        int cid = bid - 584;
        int b = cid >> 4, t0 = (cid & 15) * 64;
        int tl = tid & 63, fg = tid >> 6;
        for (int j = tid; j < 94; j += 256) {
            int tt = t0 - 15 + j;
            bool ok = (tt >= 0 && tt < T);
            sOld[j] = ok ? old_[b * T + tt] : 0.f;
            sCum[j] = ok ? cum_[b * T + tt] : 0.f;
        }
        for (int j = tid; j < KW * 2 * F_DIM; j += 256) sLK[j] = lk[j];
        __syncthreads();
        float acc[8];
        #pragma unroll
        for (int f = 0; f < 8; ++f) acc[f] = 0.f;
        for (int k = 0; k < KW; ++k) {
            float o = sOld[tl + k], c = sCum[tl + k];
            const float* lo = &sLK[(k * 2 + 0) * F_DIM + fg * 8];
            const float* lc = &sLK[(k * 2 + 1) * F_DIM + fg * 8];
            #pragma unroll
            for (int f = 0; f < 8; ++f) acc[f] += o * lo[f] + c * lc[f];
        }
        short8 pk;
        #pragma unroll
        for (int f = 0; f < 8; ++f) pk[f] = (short)f2bf(acc[f]);
        unsigned short* dst = convb + (size_t)(b * T + t0 + tl) * 64 + fg * 8;
        *(short8*)dst = pk;
        *(short8*)(dst + 32) = (short8)0;      // zero-pad
    }
}

// ================= fused GEMM + tanh + dot(v_w) -> score =================
// grid 2048 XCD-swizzled; block 128x128, BK=64, 9 chunks; 4 waves, wave 64x64
// Double-buffered LDS, one __syncthreads per K-tile (T3-minimum 2-phase):
//   iter c: issue stage(c+1) loads -> ds_read+MFMA(c) -> pack+ds_write(c+1) -> barrier
// LDS 8-slot XOR swizzle: physical 16B-slot = (logical_seg + row) & 7
// A staged fp32->bf16 in-register; conv chunk (c==8) via global_load_lds.
// A-stage slot = j*256+tid -> consecutive lanes write consecutive 16B (conflict-free).
__launch_bounds__(256, 2)
__global__ void gemm_score(const float* __restrict__ values,
                           const unsigned short* __restrict__ Bt,
                           const unsigned short* __restrict__ convb,
                           const float* __restrict__ pq,
                           const float* __restrict__ vw,
                           float* __restrict__ score) {
    __shared__ __align__(16) short sA[2][128 * 64];
    __shared__ __align__(16) short sB[2][128 * 64];
    __shared__ float sPQ[128];
    __shared__ float sVW[128];
    int tid = threadIdx.x;
    // XCD swizzle: 4 nq-siblings (same mt) land on one XCD, adjacent in time
    int x = blockIdx.x & 7, l = blockIdx.x >> 3;
    int mt = x * 64 + (l >> 2), nq = l & 3;
    int m0 = mt * 128, n0 = nq * 128;
    int b = m0 >> 10;
    if (tid < 128) { sPQ[tid] = pq[b * A_DIM + n0 + tid]; sVW[tid] = vw[n0 + tid]; }
    int w = tid >> 6, lane = tid & 63, q = lane >> 4, l15 = lane & 15;
    int wm = w & 1, wn = w >> 1;
    // per-thread staging geometry (slot = j*256+tid), hoisted
    const float* aSrc[4];
    const unsigned short* bSrc[4];
    int aSlot[4];
    #pragma unroll
    for (int j = 0; j < 4; ++j) {
        int slot = j * 256 + tid;
        int row = slot >> 3, seg = ((slot & 7) - row) & 7;
        aSrc[j] = values + (size_t)(m0 + row) * DV + seg * 8;
        bSrc[j] = Bt + (size_t)(n0 + row) * KEXT2 + seg * 8;
        aSlot[j] = slot;
    }
    f32x4 acc[4][4];
    #pragma unroll
    for (int mi = 0; mi < 4; ++mi)
        #pragma unroll
        for (int ni = 0; ni < 4; ++ni) acc[mi][ni] = (f32x4)0.f;

    // ---- prologue: stage tile 0 into buffer 0
    {
        float4 px0[4], px1[4];
        #pragma unroll
        for (int j = 0; j < 4; ++j) {
            px0[j] = *(const float4*)(aSrc[j]);
            px1[j] = *(const float4*)(aSrc[j] + 4);
        }
        #pragma unroll
        for (int j = 0; j < 4; ++j)
            LDSDMA16(bSrc[j], &sB[0][(j * 256 + w * 64) * 8]);
        #pragma unroll
        for (int j = 0; j < 4; ++j)
            *(short8*)&sA[0][aSlot[j] * 8] = pack8(px0[j], px1[j]);
    }
    __syncthreads();

    int cur = 0;
    for (int c = 0; c < NCH; ++c) {
        int nxt = cur ^ 1;
        // ---- issue stage for tile c+1 (before compute, so latency hides)
        float4 nx0[4], nx1[4];
        if (c + 1 < NCH) {
            if (c + 1 < 8) {
                #pragma unroll
                for (int j = 0; j < 4; ++j) {
                    const float* s0 = aSrc[j] + (c + 1) * 64;
                    nx0[j] = *(const float4*)s0;
                    nx1[j] = *(const float4*)(s0 + 4);
                }
            } else {
                // conv chunk: bf16 DMA straight into sA[nxt]
                #pragma unroll
                for (int j = 0; j < 4; ++j) {
                    int slot = j * 256 + tid;
                    int row = slot >> 3, seg = ((slot & 7) - row) & 7;
                    LDSDMA16(convb + (size_t)(m0 + row) * 64 + seg * 8,
                             &sA[nxt][(j * 256 + w * 64) * 8]);
                }
            }
            #pragma unroll
            for (int j = 0; j < 4; ++j)
                LDSDMA16(bSrc[j] + (c + 1) * 64, &sB[nxt][(j * 256 + w * 64) * 8]);
        }
        // ---- compute tile c from buffer cur: 2 k-halves x 16 MFMAs
        #pragma unroll
        for (int h = 0; h < 2; ++h) {
            short8 af[4], bfr[4];
            int sgl = h * 4 + q;
            #pragma unroll
            for (int mi = 0; mi < 4; ++mi) {
                int r = wm * 64 + mi * 16 + l15;
                af[mi] = *(const short8*)&sA[cur][r * 64 + (((sgl + r) & 7) << 3)];
            }
            #pragma unroll
            for (int ni = 0; ni < 4; ++ni) {
                int r = wn * 64 + ni * 16 + l15;
                bfr[ni] = *(const short8*)&sB[cur][r * 64 + (((sgl + r) & 7) << 3)];
            }
            #pragma unroll
            for (int mi = 0; mi < 4; ++mi)
                #pragma unroll
                for (int ni = 0; ni < 4; ++ni)
                    acc[mi][ni] = __builtin_amdgcn_mfma_f32_16x16x32_bf16(af[mi], bfr[ni], acc[mi][ni], 0, 0, 0);
        }
        // ---- write-late: pack staged A regs into sA[nxt] (after MFMA)
        if (c + 1 < 8) {
            #pragma unroll
            for (int j = 0; j < 4; ++j)
                *(short8*)&sA[nxt][aSlot[j] * 8] = pack8(nx0[j], nx1[j]);
        }
        __syncthreads();   // single drain per tile: B-DMA + ds_writes visible
        cur ^= 1;
    }
    // ---- epilogue: partial score over 128 cols -> atomicAdd
    #pragma unroll
    for (int mi = 0; mi < 4; ++mi) {
        #pragma unroll
        for (int r = 0; r < 4; ++r) {
            float s = 0.f;
            #pragma unroll
            for (int ni = 0; ni < 4; ++ni) {
                int col = wn * 64 + ni * 16 + l15;
                float xv = acc[mi][ni][r] + sPQ[col];
                s += tanh_fast(xv) * sVW[col];
            }
            #pragma unroll
            for (int off = 1; off < 16; off <<= 1) s += __shfl_xor(s, off, 64);
            if (l15 == 0)
                atomicAdd(&score[m0 + wm * 64 + mi * 16 + q * 4 + r], s);
        }
    }
}

// ================= softmax + forward-attention recursion =================
__global__ void softmax_fwd(const float* __restrict__ score,
                            const float* __restrict__ alpha,
                            const float* __restrict__ cum,
                            float* __restrict__ out) {
    int b = blockIdx.x, t = threadIdx.x;   // 1024 threads
    __shared__ float sred[16];
    __shared__ float sbc;
    float sc = score[b * T + t];
    int wid = t >> 6, lane = t & 63;
    float m = sc;
    #pragma unroll
    for (int off = 32; off; off >>= 1) m = fmaxf(m, __shfl_xor(m, off, 64));
    if (lane == 0) sred[wid] = m;
    __syncthreads();
    if (t == 0) { float mm = sred[0]; for (int i = 1; i < 16; ++i) mm = fmaxf(mm, sred[i]); sbc = mm; }
    __syncthreads();
    float M = sbc;
    float e = __expf(sc - M);
    float s = e;
    #pragma unroll
    for (int off = 32; off; off >>= 1) s += __shfl_xor(s, off, 64);
    __syncthreads();
    if (lane == 0) sred[wid] = s;
    __syncthreads();
    if (t == 0) { float ss = 0.f; for (int i = 0; i < 16; ++i) ss += sred[i]; sbc = ss; }
    __syncthreads();
    float sn = e / sbc;
    float a_t = alpha[b * T + t];
    float a_p = (t > 0) ? alpha[b * T + t - 1] : 0.f;
    float ua = (0.5f * (a_t + a_p) + 1e-8f) * sn;
    float u = ua;
    #pragma unroll
    for (int off = 32; off; off >>= 1) u += __shfl_xor(u, off, 64);
    __syncthreads();
    if (lane == 0) sred[wid] = u;
    __syncthreads();
    if (t == 0) { float ss = 0.f; for (int i = 0; i < 16; ++i) ss += sred[i]; sbc = ss; }
    __syncthreads();
    float wgt = ua / sbc;
    float* attnw  = out + B * DV;
    float* ncum   = attnw + B * T;
    float* nold   = ncum + B * T;
    float* nalpha = nold + B * T;
    attnw[b * T + t]  = wgt;
    ncum[b * T + t]   = cum[b * T + t] + sn;
    nold[b * T + t]   = wgt;
    nalpha[b * T + t] = wgt;
    if (t < DV) out[b * DV + t] = 0.f;   // zero context region for accumulation
}

// ================= context = attn_weights @ values (fp32) =================
// grid 512 = 64 b x 4 tq(256 t) x 2 dh(256 d); thr: sub=tid>>6 (t-slice), dg=tid&63 (4 d)
__global__ void context_kernel(const float* __restrict__ values,
                               float* __restrict__ out) {
    __shared__ float red[4][256];
    const float* attnw = out + B * DV;
    int b = blockIdx.x >> 3, tq = (blockIdx.x >> 1) & 3, dh = blockIdx.x & 1;
    int sub = threadIdx.x >> 6, dg = threadIdx.x & 63;
    int t0 = tq * 256 + sub * 64;
    int d0 = dh * 256 + dg * 4;
    float acc[4];
    #pragma unroll
    for (int f = 0; f < 4; ++f) acc[f] = 0.f;
    for (int tt = 0; tt < 64; ++tt) {
        int t = t0 + tt;
        float wgt = attnw[b * T + t];
        float4 xv = *(const float4*)(values + (size_t)(b * T + t) * DV + d0);
        acc[0] += wgt * xv.x; acc[1] += wgt * xv.y;
        acc[2] += wgt * xv.z; acc[3] += wgt * xv.w;
    }
    #pragma unroll
    for (int f = 0; f < 4; ++f) red[sub][dg * 4 + f] = acc[f];
    __syncthreads();
    if (sub == 0) {
        #pragma unroll
        for (int f = 0; f < 4; ++f) {
            int di = dg * 4 + f;
            float s = red[0][di] + red[1][di] + red[2][di] + red[3][di];
            atomicAdd(&out[b * DV + dh * 256 + di], s);
        }
    }
}

extern "C" void kernel_launch(void* const* d_in, const int* in_sizes, int n_in,
                              void* d_out, int out_size, void* d_ws, size_t ws_size,
                              hipStream_t stream) {
    const float* query  = (const float*)d_in[0];
    const float* values = (const float*)d_in[1];
    const float* cum    = (const float*)d_in[2];
    const float* old_   = (const float*)d_in[3];
    const float* alpha  = (const float*)d_in[4];
    const float* Wq     = (const float*)d_in[5];
    const float* Wi     = (const float*)d_in[6];
    const float* vw     = (const float*)d_in[7];
    // d_in[8] = v_b : dropped (softmax shift-invariant)
    const float* lk     = (const float*)d_in[9];
    const float* Wl     = (const float*)d_in[10];
    float* out = (float*)d_out;
    char* ws = (char*)d_ws;
    float* ws_pq            = (float*)(ws);                     // 128 KiB
    float* ws_score         = (float*)(ws + 131072);            // 256 KiB
    unsigned short* ws_Bt   = (unsigned short*)(ws + 393216);   // 512*576*2 = 576 KiB
    unsigned short* ws_conv = (unsigned short*)(ws + 1048576);  // 65536*64*2 = 8 MiB

    prep_kernel<<<1608, 256, 0, stream>>>(query, Wq, Wi, Wl, old_, cum, lk,
                                          ws_pq, ws_score, ws_Bt, ws_conv);
    gemm_score<<<2048, 256, 0, stream>>>(values, ws_Bt, ws_conv, ws_pq, vw, ws_score);
    softmax_fwd<<<64, 1024, 0, stream>>>(ws_score, alpha, cum, out);
    context_kernel<<<512, 256, 0, stream>>>(values, out);
}

// Round 4
// 298.851 us; speedup vs baseline: 1.0850x; 1.0676x over previous
//
#include <hip/hip_runtime.h>
#include <hip/hip_bf16.h>
#include <cstdint>
#include <cstddef>

#define B 64
#define T 1024
#define DQ 1024
#define DV 512
#define A_DIM 512
#define F_DIM 32
#define KW 31
#define M_TOT (B*T)
#define KEXT2 576     // DV + 64 (conv 32 + zero-pad 32)
#define NCH 9         // 9 chunks of K=64 (last = conv+pad)

typedef __attribute__((ext_vector_type(8))) short short8;
typedef __attribute__((ext_vector_type(4))) float f32x4;

static __device__ __forceinline__ unsigned short f2bf(float f) {
    unsigned int u = __builtin_bit_cast(unsigned int, f);
    u += 0x7fffu + ((u >> 16) & 1u);   // RNE
    return (unsigned short)(u >> 16);
}
static __device__ __forceinline__ float tanh_fast(float x) {
    float e = __expf(2.0f * x);
    return 1.0f - 2.0f * __builtin_amdgcn_rcpf(e + 1.0f);
}
// packed fp32->bf16 (RNE) pair in one u32
static __device__ __forceinline__ unsigned cvtpk(float lo, float hi) {
    return (unsigned)f2bf(lo) | ((unsigned)f2bf(hi) << 16);
}
static __device__ __forceinline__ short8 cvt8(f32x4 a, f32x4 b) {
    unsigned u0 = cvtpk(a[0], a[1]), u1 = cvtpk(a[2], a[3]);
    unsigned u2 = cvtpk(b[0], b[1]), u3 = cvtpk(b[2], b[3]);
    short8 r;
    r[0] = (short)(u0 & 0xffff); r[1] = (short)(u0 >> 16);
    r[2] = (short)(u1 & 0xffff); r[3] = (short)(u1 >> 16);
    r[4] = (short)(u2 & 0xffff); r[5] = (short)(u2 >> 16);
    r[6] = (short)(u3 & 0xffff); r[7] = (short)(u3 >> 16);
    return r;
}

// async global -> LDS, 16 B per lane; lptr wave-uniform base, lane i -> +i*16
#define LDSDMA16(gptr, lptr)                                                        \
    __builtin_amdgcn_global_load_lds(                                               \
        (const __attribute__((address_space(1))) void*)(const void*)(gptr),         \
        (__attribute__((address_space(3))) void*)(void*)(lptr), 16, 0, 0)

// ================= prep (no values pass) =================
// blocks [0,512): pq + score zero   [512,584): B_ext^T transpose
// [584,1608): location conv
__global__ void prep_kernel(const float* __restrict__ query, const float* __restrict__ Wq,
                            const float* __restrict__ Wi, const float* __restrict__ Wl,
                            const float* __restrict__ old_, const float* __restrict__ cum_,
                            const float* __restrict__ lk,
                            float* __restrict__ pq,
                            float* __restrict__ score, unsigned short* __restrict__ Bt,
                            unsigned short* __restrict__ convb) {
    __shared__ __align__(16) char smem[16640];
    int bid = blockIdx.x, tid = threadIdx.x;
    if (bid < 512) {
        // ---- pq + zero score ----
        float (*red)[64] = (float(*)[64])smem;
        int pid = bid;
        int gid = pid * 256 + tid;
        if (gid < M_TOT) score[gid] = 0.f;
        int b = pid >> 3, a0 = (pid & 7) * 64;
        int al = tid & 63, ks = tid >> 6;
        const float* qr = query + (size_t)b * DQ + ks * 256;
        const float* wc = Wq + (size_t)(ks * 256) * A_DIM + a0 + al;
        float acc = 0.f;
        #pragma unroll 8
        for (int k = 0; k < 256; ++k) acc += qr[k] * wc[(size_t)k * A_DIM];
        red[ks][al] = acc;
        __syncthreads();
        if (ks == 0)
            pq[b * A_DIM + a0 + al] = red[0][al] + red[1][al] + red[2][al] + red[3][al];
    } else if (bid < 584) {
        // ---- Bt transpose (stride KEXT2=576) ----
        float (*tile)[65] = (float(*)[65])smem;
        int tb = bid - 512;
        if (tb < 64) {
            int k0 = (tb >> 3) * 64, a0 = (tb & 7) * 64;
            int al = tid & 63, ko = tid >> 6;
            #pragma unroll
            for (int j = 0; j < 16; ++j) {
                int kl = j * 4 + ko;
                tile[kl][al] = Wi[(size_t)(k0 + kl) * A_DIM + a0 + al];
            }
            __syncthreads();
            int kl2 = tid & 63, ao = tid >> 6;
            #pragma unroll
            for (int j = 0; j < 16; ++j) {
                int al2 = j * 4 + ao;
                Bt[(size_t)(a0 + al2) * KEXT2 + k0 + kl2] = f2bf(tile[kl2][al2]);
            }
        } else {
            int a0 = (tb - 64) * 64;
            int al = tid & 63, ko = tid >> 6;
            #pragma unroll
            for (int j = 0; j < 8; ++j) {
                int kl = j * 4 + ko;
                tile[kl][al] = Wl[(size_t)kl * A_DIM + a0 + al];
            }
            __syncthreads();
            int kl2 = tid & 31, ao = tid >> 5;
            #pragma unroll
            for (int j = 0; j < 8; ++j) {
                int al2 = j * 8 + ao;
                Bt[(size_t)(a0 + al2) * KEXT2 + DV + kl2] = f2bf(tile[kl2][al2]);
            }
            // zero-pad k in [544,576)
            #pragma unroll
            for (int j = 0; j < 8; ++j) {
                int idx = j * 256 + tid;
                int a_l = idx >> 5, kp = idx & 31;
                Bt[(size_t)(a0 + a_l) * KEXT2 + 544 + kp] = 0;
            }
        }
    } else {
        // ---- conv (rows widened to 64: [32 conv | 32 zeros]) ----
        float* sOld = (float*)smem;            // 94
        float* sCum = sOld + 94;               // 94
        float* sLK  = sCum + 94;               // 1984
        int cid = bid - 584;
        int b = cid >> 4, t0 = (cid & 15) * 64;
        int tl = tid & 63, fg = tid >> 6;
        for (int j = tid; j < 94; j += 256) {
            int tt = t0 - 15 + j;
            bool ok = (tt >= 0 && tt < T);
            sOld[j] = ok ? old_[b * T + tt] : 0.f;
            sCum[j] = ok ? cum_[b * T + tt] : 0.f;
        }
        for (int j = tid; j < KW * 2 * F_DIM; j += 256) sLK[j] = lk[j];
        __syncthreads();
        float acc[8];
        #pragma unroll
        for (int f = 0; f < 8; ++f) acc[f] = 0.f;
        for (int k = 0; k < KW; ++k) {
            float o = sOld[tl + k], c = sCum[tl + k];
            const float* lo = &sLK[(k * 2 + 0) * F_DIM + fg * 8];
            const float* lc = &sLK[(k * 2 + 1) * F_DIM + fg * 8];
            #pragma unroll
            for (int f = 0; f < 8; ++f) acc[f] += o * lo[f] + c * lc[f];
        }
        short8 pk;
        #pragma unroll
        for (int f = 0; f < 8; ++f) pk[f] = (short)f2bf(acc[f]);
        unsigned short* dst = convb + (size_t)(b * T + t0 + tl) * 64 + fg * 8;
        *(short8*)dst = pk;
        *(short8*)(dst + 32) = (short8)0;      // zero-pad
    }
}

// ================= fused GEMM + tanh + dot(v_w) -> score =================
// grid 2048 XCD-swizzled; block 128x128, BK=64, 9 chunks; 4 waves, wave 64x64
// m97 single-buffer 2-barrier structure, 3 blocks/CU overlap:
//   chunk c: barrier -> DMA-stage A(fp32)+B(bf16) -> barrier -> ds_read+cvt+MFMA
// A staged fp32 via global_load_lds (32KB), converted to bf16 at fragment read.
// A LDS swizzle: phys 16B-slot = s ^ (row&15), applied by pre-swizzling the
// per-lane global source; reads use the same XOR -> 2-way (free).
// B/conv: bf16 8-slot swizzle phys = (seg+row)&7 as before.
__launch_bounds__(256, 3)
__global__ void gemm_score(const float* __restrict__ values,
                           const unsigned short* __restrict__ Bt,
                           const unsigned short* __restrict__ convb,
                           const float* __restrict__ pq,
                           const float* __restrict__ vw,
                           float* __restrict__ score) {
    __shared__ __align__(16) float sAf[128 * 64];   // 32KB fp32 A chunk (aliased bf16 for conv)
    __shared__ __align__(16) short sB[128 * 64];    // 16KB bf16 B chunk
    __shared__ float sPQ[128];
    __shared__ float sVW[128];
    int tid = threadIdx.x;
    // XCD swizzle: 4 nq-siblings (same mt) land on one XCD, adjacent in time
    int x = blockIdx.x & 7, l = blockIdx.x >> 3;
    int mt = x * 64 + (l >> 2), nq = l & 3;
    int m0 = mt * 128, n0 = nq * 128;
    int b = m0 >> 10;
    if (tid < 128) { sPQ[tid] = pq[b * A_DIM + n0 + tid]; sVW[tid] = vw[n0 + tid]; }
    int w = tid >> 6, lane = tid & 63, q = lane >> 4, l15 = lane & 15;
    int wm = w & 1, wn = w >> 1;
    // A stage: linear slot P=j*256+tid -> row=j*16+(tid>>4); phys slot (tid&15)
    // receives logical slot s=(tid&15)^row  (row&15 == tid>>4)
    int trow = tid >> 4, pA = tid & 15;
    const float* aBase = values + (size_t)(m0 + trow) * DV + (pA ^ trow) * 4;
    // B/conv stage: slot=j*256+tid -> row=j*32+(tid>>3); phys (tid&7) holds seg
    int brow = tid >> 3, bseg = ((tid & 7) - brow) & 7;
    const unsigned short* bBase = Bt + (size_t)(n0 + brow) * KEXT2 + bseg * 8;
    const unsigned short* cBase = convb + (size_t)(m0 + brow) * 64 + bseg * 8;

    f32x4 acc[4][4];
    #pragma unroll
    for (int mi = 0; mi < 4; ++mi)
        #pragma unroll
        for (int ni = 0; ni < 4; ++ni) acc[mi][ni] = (f32x4)0.f;

    for (int c = 0; c < NCH; ++c) {
        __syncthreads();                    // previous chunk's compute done
        if (c < 8) {
            #pragma unroll
            for (int j = 0; j < 8; ++j)
                LDSDMA16(aBase + (size_t)j * 16 * DV + c * 64,
                         &sAf[(j * 256 + w * 64) * 4]);
        } else {
            #pragma unroll
            for (int j = 0; j < 4; ++j)
                LDSDMA16(cBase + j * 32 * 64,
                         (short*)sAf + (j * 256 + w * 64) * 8);
        }
        #pragma unroll
        for (int j = 0; j < 4; ++j)
            LDSDMA16(bBase + (size_t)j * 32 * KEXT2 + c * 64,
                     &sB[(j * 256 + w * 64) * 8]);
        __syncthreads();                    // DMA drained (vmcnt(0) at barrier)
        // ---- 2 k-halves x 16 MFMAs
        #pragma unroll
        for (int h = 0; h < 2; ++h) {
            short8 af[4], bfr[4];
            #pragma unroll
            for (int ni = 0; ni < 4; ++ni) {
                int r = wn * 64 + ni * 16 + l15;
                bfr[ni] = *(const short8*)&sB[r * 64 + ((((h * 4 + q) + r) & 7) << 3)];
            }
            if (c < 8) {
                #pragma unroll
                for (int mi = 0; mi < 4; ++mi) {
                    int r = wm * 64 + mi * 16 + l15;
                    int ps = (h * 8 + q * 2) ^ l15;
                    f32x4 lo = *(const f32x4*)&sAf[r * 64 + ps * 4];
                    f32x4 hi = *(const f32x4*)&sAf[r * 64 + (ps ^ 1) * 4];
                    af[mi] = cvt8(lo, hi);
                }
            } else {
                const short* sAh = (const short*)sAf;
                #pragma unroll
                for (int mi = 0; mi < 4; ++mi) {
                    int r = wm * 64 + mi * 16 + l15;
                    af[mi] = *(const short8*)&sAh[r * 64 + ((((h * 4 + q) + r) & 7) << 3)];
                }
            }
            #pragma unroll
            for (int mi = 0; mi < 4; ++mi)
                #pragma unroll
                for (int ni = 0; ni < 4; ++ni)
                    acc[mi][ni] = __builtin_amdgcn_mfma_f32_16x16x32_bf16(af[mi], bfr[ni], acc[mi][ni], 0, 0, 0);
        }
    }
    // ---- epilogue: partial score over 128 cols -> atomicAdd
    #pragma unroll
    for (int mi = 0; mi < 4; ++mi) {
        #pragma unroll
        for (int r = 0; r < 4; ++r) {
            float s = 0.f;
            #pragma unroll
            for (int ni = 0; ni < 4; ++ni) {
                int col = wn * 64 + ni * 16 + l15;
                float xv = acc[mi][ni][r] + sPQ[col];
                s += tanh_fast(xv) * sVW[col];
            }
            #pragma unroll
            for (int off = 1; off < 16; off <<= 1) s += __shfl_xor(s, off, 64);
            if (l15 == 0)
                atomicAdd(&score[m0 + wm * 64 + mi * 16 + q * 4 + r], s);
        }
    }
}

// ================= softmax + forward-attention recursion =================
__global__ void softmax_fwd(const float* __restrict__ score,
                            const float* __restrict__ alpha,
                            const float* __restrict__ cum,
                            float* __restrict__ out) {
    int b = blockIdx.x, t = threadIdx.x;   // 1024 threads
    __shared__ float sred[16];
    __shared__ float sbc;
    float sc = score[b * T + t];
    int wid = t >> 6, lane = t & 63;
    float m = sc;
    #pragma unroll
    for (int off = 32; off; off >>= 1) m = fmaxf(m, __shfl_xor(m, off, 64));
    if (lane == 0) sred[wid] = m;
    __syncthreads();
    if (t == 0) { float mm = sred[0]; for (int i = 1; i < 16; ++i) mm = fmaxf(mm, sred[i]); sbc = mm; }
    __syncthreads();
    float M = sbc;
    float e = __expf(sc - M);
    float s = e;
    #pragma unroll
    for (int off = 32; off; off >>= 1) s += __shfl_xor(s, off, 64);
    __syncthreads();
    if (lane == 0) sred[wid] = s;
    __syncthreads();
    if (t == 0) { float ss = 0.f; for (int i = 0; i < 16; ++i) ss += sred[i]; sbc = ss; }
    __syncthreads();
    float sn = e / sbc;
    float a_t = alpha[b * T + t];
    float a_p = (t > 0) ? alpha[b * T + t - 1] : 0.f;
    float ua = (0.5f * (a_t + a_p) + 1e-8f) * sn;
    float u = ua;
    #pragma unroll
    for (int off = 32; off; off >>= 1) u += __shfl_xor(u, off, 64);
    __syncthreads();
    if (lane == 0) sred[wid] = u;
    __syncthreads();
    if (t == 0) { float ss = 0.f; for (int i = 0; i < 16; ++i) ss += sred[i]; sbc = ss; }
    __syncthreads();
    float wgt = ua / sbc;
    float* attnw  = out + B * DV;
    float* ncum   = attnw + B * T;
    float* nold   = ncum + B * T;
    float* nalpha = nold + B * T;
    attnw[b * T + t]  = wgt;
    ncum[b * T + t]   = cum[b * T + t] + sn;
    nold[b * T + t]   = wgt;
    nalpha[b * T + t] = wgt;
    if (t < DV) out[b * DV + t] = 0.f;   // zero context region for accumulation
}

// ================= context = attn_weights @ values (fp32) =================
// grid 2048 = 64 b x 16 tq(64 t) x 2 dh(256 d); thr: sub=tid>>6 (16-t slice), dg=tid&63
__global__ void context_kernel(const float* __restrict__ values,
                               float* __restrict__ out) {
    __shared__ float red[4][256];
    const float* attnw = out + B * DV;
    int b = blockIdx.x >> 5, tq = (blockIdx.x >> 1) & 15, dh = blockIdx.x & 1;
    int sub = threadIdx.x >> 6, dg = threadIdx.x & 63;
    int t0 = tq * 64 + sub * 16;
    int d0 = dh * 256 + dg * 4;
    float acc[4];
    #pragma unroll
    for (int f = 0; f < 4; ++f) acc[f] = 0.f;
    for (int tt = 0; tt < 16; ++tt) {
        int t = t0 + tt;
        float wgt = attnw[b * T + t];
        float4 xv = *(const float4*)(values + (size_t)(b * T + t) * DV + d0);
        acc[0] += wgt * xv.x; acc[1] += wgt * xv.y;
        acc[2] += wgt * xv.z; acc[3] += wgt * xv.w;
    }
    #pragma unroll
    for (int f = 0; f < 4; ++f) red[sub][dg * 4 + f] = acc[f];
    __syncthreads();
    if (sub == 0) {
        #pragma unroll
        for (int f = 0; f < 4; ++f) {
            int di = dg * 4 + f;
            float s = red[0][di] + red[1][di] + red[2][di] + red[3][di];
            atomicAdd(&out[b * DV + dh * 256 + di], s);
        }
    }
}

extern "C" void kernel_launch(void* const* d_in, const int* in_sizes, int n_in,
                              void* d_out, int out_size, void* d_ws, size_t ws_size,
                              hipStream_t stream) {
    const float* query  = (const float*)d_in[0];
    const float* values = (const float*)d_in[1];
    const float* cum    = (const float*)d_in[2];
    const float* old_   = (const float*)d_in[3];
    const float* alpha  = (const float*)d_in[4];
    const float* Wq     = (const float*)d_in[5];
    const float* Wi     = (const float*)d_in[6];
    const float* vw     = (const float*)d_in[7];
    // d_in[8] = v_b : dropped (softmax shift-invariant)
    const float* lk     = (const float*)d_in[9];
    const float* Wl     = (const float*)d_in[10];
    float* out = (float*)d_out;
    char* ws = (char*)d_ws;
    float* ws_pq            = (float*)(ws);                     // 128 KiB
    float* ws_score         = (float*)(ws + 131072);            // 256 KiB
    unsigned short* ws_Bt   = (unsigned short*)(ws + 393216);   // 512*576*2 = 576 KiB
    unsigned short* ws_conv = (unsigned short*)(ws + 1048576);  // 65536*64*2 = 8 MiB

    prep_kernel<<<1608, 256, 0, stream>>>(query, Wq, Wi, Wl, old_, cum, lk,
                                          ws_pq, ws_score, ws_Bt, ws_conv);
    gemm_score<<<2048, 256, 0, stream>>>(values, ws_Bt, ws_conv, ws_pq, vw, ws_score);
    softmax_fwd<<<64, 1024, 0, stream>>>(ws_score, alpha, cum, out);
    context_kernel<<<2048, 256, 0, stream>>>(values, out);
}

// Round 5
// 295.901 us; speedup vs baseline: 1.0958x; 1.0100x over previous
//
#include <hip/hip_runtime.h>
#include <hip/hip_bf16.h>
#include <cstdint>
#include <cstddef>

#define B 64
#define T 1024
#define DQ 1024
#define DV 512
#define A_DIM 512
#define F_DIM 32
#define KW 31
#define M_TOT (B*T)
#define KEXT2 576     // DV + 64 (conv 32 + zero-pad 32)
#define NCH 9         // 9 chunks of K=64 (last = conv+pad)

typedef __attribute__((ext_vector_type(8))) short short8;
typedef __attribute__((ext_vector_type(4))) float f32x4;
typedef __attribute__((ext_vector_type(4))) unsigned u32x4;

static __device__ __forceinline__ unsigned short f2bf(float f) {
    unsigned int u = __builtin_bit_cast(unsigned int, f);
    u += 0x7fffu + ((u >> 16) & 1u);   // RNE
    return (unsigned short)(u >> 16);
}
static __device__ __forceinline__ float tanh_fast(float x) {
    float e = __expf(2.0f * x);
    return 1.0f - 2.0f * __builtin_amdgcn_rcpf(e + 1.0f);
}
// hardware packed fp32->bf16: one v_cvt_pk_bf16_f32 per element-pair
static __device__ __forceinline__ short8 cvt8(f32x4 a, f32x4 b) {
    unsigned u0, u1, u2, u3;
    asm("v_cvt_pk_bf16_f32 %0, %1, %2" : "=v"(u0) : "v"(a[0]), "v"(a[1]));
    asm("v_cvt_pk_bf16_f32 %0, %1, %2" : "=v"(u1) : "v"(a[2]), "v"(a[3]));
    asm("v_cvt_pk_bf16_f32 %0, %1, %2" : "=v"(u2) : "v"(b[0]), "v"(b[1]));
    asm("v_cvt_pk_bf16_f32 %0, %1, %2" : "=v"(u3) : "v"(b[2]), "v"(b[3]));
    u32x4 u; u[0] = u0; u[1] = u1; u[2] = u2; u[3] = u3;
    return __builtin_bit_cast(short8, u);
}

// async global -> LDS, 16 B per lane; lptr wave-uniform base, lane i -> +i*16
#define LDSDMA16(gptr, lptr)                                                        \
    __builtin_amdgcn_global_load_lds(                                               \
        (const __attribute__((address_space(1))) void*)(const void*)(gptr),         \
        (__attribute__((address_space(3))) void*)(void*)(lptr), 16, 0, 0)

// ================= prep (no values pass) =================
// blocks [0,512): pq + score zero   [512,584): B_ext^T transpose
// [584,1608): location conv
__global__ void prep_kernel(const float* __restrict__ query, const float* __restrict__ Wq,
                            const float* __restrict__ Wi, const float* __restrict__ Wl,
                            const float* __restrict__ old_, const float* __restrict__ cum_,
                            const float* __restrict__ lk,
                            float* __restrict__ pq,
                            float* __restrict__ score, unsigned short* __restrict__ Bt,
                            unsigned short* __restrict__ convb) {
    __shared__ __align__(16) char smem[16640];
    int bid = blockIdx.x, tid = threadIdx.x;
    if (bid < 512) {
        // ---- pq + zero score ----
        float (*red)[64] = (float(*)[64])smem;
        int pid = bid;
        int gid = pid * 256 + tid;
        if (gid < M_TOT) score[gid] = 0.f;
        int b = pid >> 3, a0 = (pid & 7) * 64;
        int al = tid & 63, ks = tid >> 6;
        const float* qr = query + (size_t)b * DQ + ks * 256;
        const float* wc = Wq + (size_t)(ks * 256) * A_DIM + a0 + al;
        float acc = 0.f;
        #pragma unroll 8
        for (int k = 0; k < 256; ++k) acc += qr[k] * wc[(size_t)k * A_DIM];
        red[ks][al] = acc;
        __syncthreads();
        if (ks == 0)
            pq[b * A_DIM + a0 + al] = red[0][al] + red[1][al] + red[2][al] + red[3][al];
    } else if (bid < 584) {
        // ---- Bt transpose (stride KEXT2=576) ----
        float (*tile)[65] = (float(*)[65])smem;
        int tb = bid - 512;
        if (tb < 64) {
            int k0 = (tb >> 3) * 64, a0 = (tb & 7) * 64;
            int al = tid & 63, ko = tid >> 6;
            #pragma unroll
            for (int j = 0; j < 16; ++j) {
                int kl = j * 4 + ko;
                tile[kl][al] = Wi[(size_t)(k0 + kl) * A_DIM + a0 + al];
            }
            __syncthreads();
            int kl2 = tid & 63, ao = tid >> 6;
            #pragma unroll
            for (int j = 0; j < 16; ++j) {
                int al2 = j * 4 + ao;
                Bt[(size_t)(a0 + al2) * KEXT2 + k0 + kl2] = f2bf(tile[kl2][al2]);
            }
        } else {
            int a0 = (tb - 64) * 64;
            int al = tid & 63, ko = tid >> 6;
            #pragma unroll
            for (int j = 0; j < 8; ++j) {
                int kl = j * 4 + ko;
                tile[kl][al] = Wl[(size_t)kl * A_DIM + a0 + al];
            }
            __syncthreads();
            int kl2 = tid & 31, ao = tid >> 5;
            #pragma unroll
            for (int j = 0; j < 8; ++j) {
                int al2 = j * 8 + ao;
                Bt[(size_t)(a0 + al2) * KEXT2 + DV + kl2] = f2bf(tile[kl2][al2]);
            }
            // zero-pad k in [544,576)
            #pragma unroll
            for (int j = 0; j < 8; ++j) {
                int idx = j * 256 + tid;
                int a_l = idx >> 5, kp = idx & 31;
                Bt[(size_t)(a0 + a_l) * KEXT2 + 544 + kp] = 0;
            }
        }
    } else {
        // ---- conv (rows widened to 64: [32 conv | 32 zeros]) ----
        float* sOld = (float*)smem;            // 94
        float* sCum = sOld + 94;               // 94
        float* sLK  = sCum + 94;               // 1984
        int cid = bid - 584;
        int b = cid >> 4, t0 = (cid & 15) * 64;
        int tl = tid & 63, fg = tid >> 6;
        for (int j = tid; j < 94; j += 256) {
            int tt = t0 - 15 + j;
            bool ok = (tt >= 0 && tt < T);
            sOld[j] = ok ? old_[b * T + tt] : 0.f;
            sCum[j] = ok ? cum_[b * T + tt] : 0.f;
        }
        for (int j = tid; j < KW * 2 * F_DIM; j += 256) sLK[j] = lk[j];
        __syncthreads();
        float acc[8];
        #pragma unroll
        for (int f = 0; f < 8; ++f) acc[f] = 0.f;
        for (int k = 0; k < KW; ++k) {
            float o = sOld[tl + k], c = sCum[tl + k];
            const float* lo = &sLK[(k * 2 + 0) * F_DIM + fg * 8];
            const float* lc = &sLK[(k * 2 + 1) * F_DIM + fg * 8];
            #pragma unroll
            for (int f = 0; f < 8; ++f) acc[f] += o * lo[f] + c * lc[f];
        }
        short8 pk;
        #pragma unroll
        for (int f = 0; f < 8; ++f) pk[f] = (short)f2bf(acc[f]);
        unsigned short* dst = convb + (size_t)(b * T + t0 + tl) * 64 + fg * 8;
        *(short8*)dst = pk;
        *(short8*)(dst + 32) = (short8)0;      // zero-pad
    }
}

// ================= fused GEMM + tanh + dot(v_w) -> score =================
// grid 2048 XCD-swizzled; block 128x128, BK=64, 9 chunks; 4 waves, wave 64x64
// m97 single-buffer 2-barrier structure, 3 blocks/CU overlap:
//   chunk c: barrier -> DMA-stage A(fp32)+B(bf16) -> barrier -> ds_read+cvt+MFMA
// A staged fp32 via global_load_lds (32KB), converted to bf16 at fragment read
// with hardware v_cvt_pk_bf16_f32 (4 instrs/fragment).
// A LDS swizzle: phys 16B-slot = s ^ (row&15), applied by pre-swizzling the
// per-lane global source; reads use the same XOR -> 2-way (free).
// B/conv: bf16 8-slot swizzle phys = (seg+row)&7 as before.
__launch_bounds__(256, 3)
__global__ void gemm_score(const float* __restrict__ values,
                           const unsigned short* __restrict__ Bt,
                           const unsigned short* __restrict__ convb,
                           const float* __restrict__ pq,
                           const float* __restrict__ vw,
                           float* __restrict__ score) {
    __shared__ __align__(16) float sAf[128 * 64];   // 32KB fp32 A chunk (aliased bf16 for conv)
    __shared__ __align__(16) short sB[128 * 64];    // 16KB bf16 B chunk
    __shared__ float sPQ[128];
    __shared__ float sVW[128];
    int tid = threadIdx.x;
    // XCD swizzle: 4 nq-siblings (same mt) land on one XCD, adjacent in time
    int x = blockIdx.x & 7, l = blockIdx.x >> 3;
    int mt = x * 64 + (l >> 2), nq = l & 3;
    int m0 = mt * 128, n0 = nq * 128;
    int b = m0 >> 10;
    if (tid < 128) { sPQ[tid] = pq[b * A_DIM + n0 + tid]; sVW[tid] = vw[n0 + tid]; }
    int w = tid >> 6, lane = tid & 63, q = lane >> 4, l15 = lane & 15;
    int wm = w & 1, wn = w >> 1;
    // A stage: linear slot P=j*256+tid -> row=j*16+(tid>>4); phys slot (tid&15)
    // receives logical slot s=(tid&15)^row  (row&15 == tid>>4)
    int trow = tid >> 4, pA = tid & 15;
    const float* aBase = values + (size_t)(m0 + trow) * DV + (pA ^ trow) * 4;
    // B/conv stage: slot=j*256+tid -> row=j*32+(tid>>3); phys (tid&7) holds seg
    int brow = tid >> 3, bseg = ((tid & 7) - brow) & 7;
    const unsigned short* bBase = Bt + (size_t)(n0 + brow) * KEXT2 + bseg * 8;
    const unsigned short* cBase = convb + (size_t)(m0 + brow) * 64 + bseg * 8;

    f32x4 acc[4][4];
    #pragma unroll
    for (int mi = 0; mi < 4; ++mi)
        #pragma unroll
        for (int ni = 0; ni < 4; ++ni) acc[mi][ni] = (f32x4)0.f;

    for (int c = 0; c < NCH; ++c) {
        __syncthreads();                    // previous chunk's compute done
        if (c < 8) {
            #pragma unroll
            for (int j = 0; j < 8; ++j)
                LDSDMA16(aBase + (size_t)j * 16 * DV + c * 64,
                         &sAf[(j * 256 + w * 64) * 4]);
        } else {
            #pragma unroll
            for (int j = 0; j < 4; ++j)
                LDSDMA16(cBase + j * 32 * 64,
                         (short*)sAf + (j * 256 + w * 64) * 8);
        }
        #pragma unroll
        for (int j = 0; j < 4; ++j)
            LDSDMA16(bBase + (size_t)j * 32 * KEXT2 + c * 64,
                     &sB[(j * 256 + w * 64) * 8]);
        __syncthreads();                    // DMA drained (vmcnt(0) at barrier)
        // ---- 2 k-halves x 16 MFMAs
        #pragma unroll
        for (int h = 0; h < 2; ++h) {
            short8 af[4], bfr[4];
            #pragma unroll
            for (int ni = 0; ni < 4; ++ni) {
                int r = wn * 64 + ni * 16 + l15;
                bfr[ni] = *(const short8*)&sB[r * 64 + ((((h * 4 + q) + r) & 7) << 3)];
            }
            if (c < 8) {
                #pragma unroll
                for (int mi = 0; mi < 4; ++mi) {
                    int r = wm * 64 + mi * 16 + l15;
                    int ps = (h * 8 + q * 2) ^ l15;
                    f32x4 lo = *(const f32x4*)&sAf[r * 64 + ps * 4];
                    f32x4 hi = *(const f32x4*)&sAf[r * 64 + (ps ^ 1) * 4];
                    af[mi] = cvt8(lo, hi);
                }
            } else {
                const short* sAh = (const short*)sAf;
                #pragma unroll
                for (int mi = 0; mi < 4; ++mi) {
                    int r = wm * 64 + mi * 16 + l15;
                    af[mi] = *(const short8*)&sAh[r * 64 + ((((h * 4 + q) + r) & 7) << 3)];
                }
            }
            #pragma unroll
            for (int mi = 0; mi < 4; ++mi)
                #pragma unroll
                for (int ni = 0; ni < 4; ++ni)
                    acc[mi][ni] = __builtin_amdgcn_mfma_f32_16x16x32_bf16(af[mi], bfr[ni], acc[mi][ni], 0, 0, 0);
        }
    }
    // ---- epilogue: partial score over 128 cols -> atomicAdd
    #pragma unroll
    for (int mi = 0; mi < 4; ++mi) {
        #pragma unroll
        for (int r = 0; r < 4; ++r) {
            float s = 0.f;
            #pragma unroll
            for (int ni = 0; ni < 4; ++ni) {
                int col = wn * 64 + ni * 16 + l15;
                float xv = acc[mi][ni][r] + sPQ[col];
                s += tanh_fast(xv) * sVW[col];
            }
            #pragma unroll
            for (int off = 1; off < 16; off <<= 1) s += __shfl_xor(s, off, 64);
            if (l15 == 0)
                atomicAdd(&score[m0 + wm * 64 + mi * 16 + q * 4 + r], s);
        }
    }
}

// ================= softmax + forward-attention recursion =================
__global__ void softmax_fwd(const float* __restrict__ score,
                            const float* __restrict__ alpha,
                            const float* __restrict__ cum,
                            float* __restrict__ out) {
    int b = blockIdx.x, t = threadIdx.x;   // 1024 threads
    __shared__ float sred[16];
    __shared__ float sbc;
    float sc = score[b * T + t];
    int wid = t >> 6, lane = t & 63;
    float m = sc;
    #pragma unroll
    for (int off = 32; off; off >>= 1) m = fmaxf(m, __shfl_xor(m, off, 64));
    if (lane == 0) sred[wid] = m;
    __syncthreads();
    if (t == 0) { float mm = sred[0]; for (int i = 1; i < 16; ++i) mm = fmaxf(mm, sred[i]); sbc = mm; }
    __syncthreads();
    float M = sbc;
    float e = __expf(sc - M);
    float s = e;
    #pragma unroll
    for (int off = 32; off; off >>= 1) s += __shfl_xor(s, off, 64);
    __syncthreads();
    if (lane == 0) sred[wid] = s;
    __syncthreads();
    if (t == 0) { float ss = 0.f; for (int i = 0; i < 16; ++i) ss += sred[i]; sbc = ss; }
    __syncthreads();
    float sn = e / sbc;
    float a_t = alpha[b * T + t];
    float a_p = (t > 0) ? alpha[b * T + t - 1] : 0.f;
    float ua = (0.5f * (a_t + a_p) + 1e-8f) * sn;
    float u = ua;
    #pragma unroll
    for (int off = 32; off; off >>= 1) u += __shfl_xor(u, off, 64);
    __syncthreads();
    if (lane == 0) sred[wid] = u;
    __syncthreads();
    if (t == 0) { float ss = 0.f; for (int i = 0; i < 16; ++i) ss += sred[i]; sbc = ss; }
    __syncthreads();
    float wgt = ua / sbc;
    float* attnw  = out + B * DV;
    float* ncum   = attnw + B * T;
    float* nold   = ncum + B * T;
    float* nalpha = nold + B * T;
    attnw[b * T + t]  = wgt;
    ncum[b * T + t]   = cum[b * T + t] + sn;
    nold[b * T + t]   = wgt;
    nalpha[b * T + t] = wgt;
    if (t < DV) out[b * DV + t] = 0.f;   // zero context region for accumulation
}

// ================= context = attn_weights @ values (fp32) =================
// grid 2048 = 64 b x 16 tq(64 t) x 2 dh(256 d); thr: sub=tid>>6 (16-t slice), dg=tid&63
__global__ void context_kernel(const float* __restrict__ values,
                               float* __restrict__ out) {
    __shared__ float red[4][256];
    const float* attnw = out + B * DV;
    int b = blockIdx.x >> 5, tq = (blockIdx.x >> 1) & 15, dh = blockIdx.x & 1;
    int sub = threadIdx.x >> 6, dg = threadIdx.x & 63;
    int t0 = tq * 64 + sub * 16;
    int d0 = dh * 256 + dg * 4;
    float acc[4];
    #pragma unroll
    for (int f = 0; f < 4; ++f) acc[f] = 0.f;
    for (int tt = 0; tt < 16; ++tt) {
        int t = t0 + tt;
        float wgt = attnw[b * T + t];
        float4 xv = *(const float4*)(values + (size_t)(b * T + t) * DV + d0);
        acc[0] += wgt * xv.x; acc[1] += wgt * xv.y;
        acc[2] += wgt * xv.z; acc[3] += wgt * xv.w;
    }
    #pragma unroll
    for (int f = 0; f < 4; ++f) red[sub][dg * 4 + f] = acc[f];
    __syncthreads();
    if (sub == 0) {
        #pragma unroll
        for (int f = 0; f < 4; ++f) {
            int di = dg * 4 + f;
            float s = red[0][di] + red[1][di] + red[2][di] + red[3][di];
            atomicAdd(&out[b * DV + dh * 256 + di], s);
        }
    }
}

extern "C" void kernel_launch(void* const* d_in, const int* in_sizes, int n_in,
                              void* d_out, int out_size, void* d_ws, size_t ws_size,
                              hipStream_t stream) {
    const float* query  = (const float*)d_in[0];
    const float* values = (const float*)d_in[1];
    const float* cum    = (const float*)d_in[2];
    const float* old_   = (const float*)d_in[3];
    const float* alpha  = (const float*)d_in[4];
    const float* Wq     = (const float*)d_in[5];
    const float* Wi     = (const float*)d_in[6];
    const float* vw     = (const float*)d_in[7];
    // d_in[8] = v_b : dropped (softmax shift-invariant)
    const float* lk     = (const float*)d_in[9];
    const float* Wl     = (const float*)d_in[10];
    float* out = (float*)d_out;
    char* ws = (char*)d_ws;
    float* ws_pq            = (float*)(ws);                     // 128 KiB
    float* ws_score         = (float*)(ws + 131072);            // 256 KiB
    unsigned short* ws_Bt   = (unsigned short*)(ws + 393216);   // 512*576*2 = 576 KiB
    unsigned short* ws_conv = (unsigned short*)(ws + 1048576);  // 65536*64*2 = 8 MiB

    prep_kernel<<<1608, 256, 0, stream>>>(query, Wq, Wi, Wl, old_, cum, lk,
                                          ws_pq, ws_score, ws_Bt, ws_conv);
    gemm_score<<<2048, 256, 0, stream>>>(values, ws_Bt, ws_conv, ws_pq, vw, ws_score);
    softmax_fwd<<<64, 1024, 0, stream>>>(ws_score, alpha, cum, out);
    context_kernel<<<2048, 256, 0, stream>>>(values, out);
}